// Round 7
// baseline (67.716 us; speedup 1.0000x reference)
//
#include <hip/hip_runtime.h>
#include <hip/hip_bf16.h>
#include <math.h>

constexpr int BATCH = 2, L = 4096, NH = 16;
constexpr int T = 128;             // chunk length
constexpr int NC = L / T;          // 32 chunks
constexpr int BH = BATCH * NH;     // 32 chains

// ws layout (bytes)
constexpr size_t S_OFF    = 0;                                   // bf16 [BH][NC][64*64] (S^T: [d][s])
constexpr size_t S_BYTES  = (size_t)BH * NC * 4096 * 2;
constexpr size_t H0_OFF   = S_OFF + S_BYTES;                     // bf16 [BH][NC][64*64] ([d][s])
constexpr size_t H0_BYTES = (size_t)BH * NC * 4096 * 2;
constexpr size_t LAM_OFF  = H0_OFF + H0_BYTES;                   // f32 [BH][NC]
constexpr size_t LAM_BYTES = (size_t)BH * NC * 4;
constexpr size_t CLS_OFF  = LAM_OFF + LAM_BYTES;                 // f32 [BH][NC][T]
constexpr size_t CLS_BYTES = (size_t)BH * NC * T * 4;
constexpr size_t ONEM_OFF = CLS_OFF + CLS_BYTES;                 // f32 [BH][NC][T]
constexpr size_t WS_BYTES = ONEM_OFF + CLS_BYTES;

typedef __attribute__((ext_vector_type(8))) short short8;
typedef __attribute__((ext_vector_type(4))) float f32x4;
typedef __attribute__((ext_vector_type(4))) unsigned int uint4v;

// f32 -> bf16 via compiler cvt path (v_cvt_pk_bf16_f32 on gfx950), RTNE
__device__ __forceinline__ unsigned short f2bf(float f) {
  union { __hip_bfloat16 h; unsigned short u; } v;
  v.h = __float2bfloat16(f);
  return v.u;
}
__device__ __forceinline__ unsigned int pk2(float a, float b) {
  union { __hip_bfloat162 h; unsigned int u; } v;
  v.h = __float22bfloat162_rn(make_float2(a, b));
  return v.u;
}
__device__ __forceinline__ float bf2f(unsigned short u) {
  union { unsigned u; float f; } v; v.u = (unsigned)u << 16;
  return v.f;
}

// swizzles (u16 units). 64-wide rows: 128B period -> (row&7). 128-wide: 256B -> (row&15).
__device__ __forceinline__ int swz64(int row, int col) {
  return row * 64 + (col ^ ((row & 7) << 3));
}
__device__ __forceinline__ int swz128(int row, int col) {
  return row * 128 + (col ^ ((row & 15) << 3));
}

__device__ __forceinline__ float alpha_formula(float Aval, float xbar, float bsq,
                                               float lab_c, float beta, float ema) {
  float ad = expf(Aval);
  float ab = 1.f - exp2f(lab_c);
  float om = 1.f - ad;
  float ns = om * om * xbar * xbar * bsq / ema;
  float boost = fmaxf(tanhf(beta * ns), 0.f);
  return fminf(fmaxf(ab + (1.f - ab) * boost, 0.01f), 0.999f);
}

// ---------------------------------------------------------------------------
// Phase 1 (MFMA, T=128): per (bh, chunk): alpha/cls/coeff;
//   S^T[d][s] = sum_{j<128} X[j][d] coeff[j] B[j][s]   (bf16 out, LDS-repacked)
// ---------------------------------------------------------------------------
__global__ __launch_bounds__(256) void phase1(
    const float* __restrict__ X, const float* __restrict__ A,
    const float* __restrict__ Bm,
    const float* __restrict__ l2ab, const float* __restrict__ l2b,
    const float* __restrict__ sema,
    unsigned short* __restrict__ Sp, float* __restrict__ lamp,
    float* __restrict__ clsp, float* __restrict__ onemp) {
  const int bid = blockIdx.x;                 // bh*NC + c
  const int bh = bid >> 5, c = bid & 31;
  const int b = bh >> 4, h = bh & 15;
  const int tid = threadIdx.x;
  const int r = tid >> 2, q = tid & 3;        // r 0..63, q 0..3

  __shared__ unsigned short Xt[64 * 128];     // X^T [d][j]; later S repack (first 8KB)
  __shared__ unsigned short Bt[64 * 128];     // (coeff B)^T [s][j]
  __shared__ float xb_s[T], bq_s[T], coeff_s[T];
  __shared__ float tot_s[2], cls127_s;

  const size_t g0 = ((size_t)(b * L + c * T) * NH + h) * 64;

  float br[32];
  #pragma unroll
  for (int half = 0; half < 2; ++half) {
    const int jr = r + 64 * half;
    const size_t grow = g0 + (size_t)jr * (NH * 64);
    float xr[16];
    #pragma unroll
    for (int i = 0; i < 4; ++i) {
      *(float4*)&xr[i * 4] = *(const float4*)(X + grow + q * 16 + i * 4);
      *(float4*)&br[half * 16 + i * 4] = *(const float4*)(Bm + grow + q * 16 + i * 4);
    }
    float sx = 0.f, sb = 0.f;
    #pragma unroll
    for (int i = 0; i < 16; ++i) {
      sx += xr[i];
      float bv = br[half * 16 + i];
      sb += bv * bv;
    }
    sx += __shfl_xor(sx, 1, 64); sx += __shfl_xor(sx, 2, 64);
    sb += __shfl_xor(sb, 1, 64); sb += __shfl_xor(sb, 2, 64);
    if (q == 0) { xb_s[jr] = sx * (1.f / 64.f); bq_s[jr] = sb * (1.f / 64.f); }
    #pragma unroll
    for (int i = 0; i < 16; ++i)
      Xt[swz128(q * 16 + i, jr)] = f2bf(xr[i]);
  }
  __syncthreads();

  // alpha + 128-wide inclusive scan of log(alpha) across waves 0,1
  float cls = 0.f, onem = 0.f;
  if (tid < 128) {
    float lab_c = fminf(fmaxf(l2ab[h], -3.32f), -0.015f);
    float beta  = exp2f(fminf(fmaxf(l2b[h], -2.f), 2.f));
    float ema   = sema[h] + 1e-6f;
    float Aval  = A[(size_t)(b * L + c * T + tid) * NH + h];
    float al = alpha_formula(Aval, xb_s[tid], bq_s[tid], lab_c, beta, ema);
    onem = 1.f - al;
    cls = logf(al);
    const int lane = tid & 63;
    #pragma unroll
    for (int off = 1; off < 64; off <<= 1) {
      float o = __shfl_up(cls, off, 64);
      if (lane >= off) cls += o;
    }
    if (lane == 63) tot_s[tid >> 6] = cls;
  }
  __syncthreads();
  if (tid < 128) {
    if (tid >= 64) cls += tot_s[0];
    if (tid == 127) cls127_s = cls;
  }
  __syncthreads();
  if (tid < 128) {
    float c127 = cls127_s;
    coeff_s[tid] = expf(c127 - cls) * onem;
    size_t cb = (size_t)bid * T;
    clsp[cb + tid]  = cls;
    onemp[cb + tid] = onem;
    if (tid == 127) lamp[bid] = expf(c127);
  }
  __syncthreads();

  // stage (coeff * B)^T
  #pragma unroll
  for (int half = 0; half < 2; ++half) {
    const int jr = r + 64 * half;
    float cf = coeff_s[jr];
    #pragma unroll
    for (int i = 0; i < 16; ++i)
      Bt[swz128(q * 16 + i, jr)] = f2bf(cf * br[half * 16 + i]);
  }
  __syncthreads();

  // MFMA: 64x64 output, K=128. Wave w owns d-rows [16w,16w+16).
  const int l = tid & 63, w = tid >> 6;
  const int tr = w * 16, lr = l & 15, kg = l >> 4;
  short8 aX[4];
  #pragma unroll
  for (int kk = 0; kk < 4; ++kk)
    aX[kk] = *(const short8*)&Xt[swz128(tr + lr, kk * 32 + kg * 8)];
  f32x4 acc[4];
  #pragma unroll
  for (int nt = 0; nt < 4; ++nt) { acc[nt][0]=0.f; acc[nt][1]=0.f; acc[nt][2]=0.f; acc[nt][3]=0.f; }
  #pragma unroll
  for (int nt = 0; nt < 4; ++nt)
    #pragma unroll
    for (int kk = 0; kk < 4; ++kk) {
      short8 f = *(const short8*)&Bt[swz128(nt * 16 + lr, kk * 32 + kg * 8)];
      acc[nt] = __builtin_amdgcn_mfma_f32_16x16x32_bf16(aX[kk], f, acc[nt], 0, 0, 0);
    }

  __syncthreads();   // all Xt/Bt fragment reads complete; Xt reusable
  unsigned short* Sl = Xt;   // 8KB repack region
  #pragma unroll
  for (int nt = 0; nt < 4; ++nt)
    #pragma unroll
    for (int reg = 0; reg < 4; ++reg)
      Sl[swz64(tr + kg * 4 + reg, nt * 16 + lr)] = f2bf(acc[nt][reg]);
  __syncthreads();

  // coalesced copy-out: 512 short8 groups
  unsigned short* Sb = Sp + (size_t)bid * 4096;
  #pragma unroll
  for (int g2 = 0; g2 < 2; ++g2) {
    int g = g2 * 256 + tid;        // 0..511
    int row = g >> 3, c8 = (g & 7) * 8;
    short8 v = *(const short8*)&Sl[swz64(row, c8)];
    *(short8*)(Sb + row * 64 + c8) = v;
  }
}

// ---------------------------------------------------------------------------
// Phase 2: exclusive chunk-scan (32 chunks); S bf16 -> h0 bf16, f32 registers.
// ---------------------------------------------------------------------------
__global__ __launch_bounds__(256) void phase2(
    const unsigned int* __restrict__ Sp, const float* __restrict__ lamp,
    unsigned int* __restrict__ H0) {
  const int gtid = blockIdx.x * 256 + threadIdx.x;   // BH*2048 threads
  const int bh = gtid >> 11;
  const int e2 = gtid & 2047;                        // u32 (pair) index in chunk
  const float* lam = lamp + (size_t)bh * NC;
  const size_t base = (size_t)bh * NC * 2048 + e2;   // u32 units
  float h0v = 0.f, h1v = 0.f;
  #pragma unroll 16
  for (int c = 0; c < NC; ++c) {
    size_t off = base + (size_t)c * 2048;
    unsigned v = Sp[off];
    H0[off] = pk2(h0v, h1v);
    float la = lam[c];
    h0v = la * h0v + bf2f((unsigned short)(v & 0xFFFFu));
    h1v = la * h1v + bf2f((unsigned short)(v >> 16));
  }
}

// ---------------------------------------------------------------------------
// Phase 3 (MFMA, T=128): Y = diag(e^cls) (C @ h0) + (W ⊙ (C @ B^T)) @ X
// 512 threads; WG[128][128] aliases the Cl+Bl LDS region after matmul2.
// ---------------------------------------------------------------------------
__global__ __launch_bounds__(512) void phase3(
    const float* __restrict__ X, const float* __restrict__ Bm,
    const float* __restrict__ Cm, const unsigned short* __restrict__ H0,
    const float* __restrict__ clsp, const float* __restrict__ onemp,
    float* __restrict__ Y) {
  const int bid = blockIdx.x;
  const int bh = bid >> 5, c = bid & 31;
  const int b = bh >> 4, h = bh & 15;
  const int tid = threadIdx.x;
  const int l = tid & 63, w = tid >> 6;   // w 0..7

  __shared__ unsigned short CB[2 * 128 * 64];  // Cl | Bl ; aliased by WG[128][128]
  __shared__ unsigned short Hl[64 * 64];       // h0^T [d][s]
  __shared__ unsigned short Xt[64 * 128];      // X^T [d][j]
  __shared__ float cl2_s[T], onem_s[T], ecls_s[T];
  unsigned short* Cl = CB;                     // C [t][s]
  unsigned short* Bl = CB + 128 * 64;          // B [j][s]
  unsigned short* WG = CB;                     // WG [t][j] (after barrier)

  const size_t g0 = ((size_t)(b * L + c * T) * NH + h) * 64;
  const int r = tid >> 2, q = tid & 3;         // r 0..127
  const size_t grow = g0 + (size_t)r * (NH * 64);
  const unsigned short* h0p = H0 + (size_t)bid * 4096;

  #pragma unroll
  for (int i = 0; i < 2; ++i) {
    int col = q * 16 + i * 8;
    float4 c0 = *(const float4*)(Cm + grow + col);
    float4 c1 = *(const float4*)(Cm + grow + col + 4);
    float4 b0 = *(const float4*)(Bm + grow + col);
    float4 b1 = *(const float4*)(Bm + grow + col + 4);
    float4 x0 = *(const float4*)(X + grow + col);
    float4 x1 = *(const float4*)(X + grow + col + 4);
    int o = swz64(r, col);
    uint4v cv = { pk2(c0.x, c0.y), pk2(c0.z, c0.w), pk2(c1.x, c1.y), pk2(c1.z, c1.w) };
    uint4v bv = { pk2(b0.x, b0.y), pk2(b0.z, b0.w), pk2(b1.x, b1.y), pk2(b1.z, b1.w) };
    *(uint4v*)&Cl[o] = cv;
    *(uint4v*)&Bl[o] = bv;
    if (r < 64) {
      short8 hv = *(const short8*)(h0p + (size_t)r * 64 + col);
      *(short8*)&Hl[o] = hv;
    }
    float xs[8] = {x0.x, x0.y, x0.z, x0.w, x1.x, x1.y, x1.z, x1.w};
    #pragma unroll
    for (int ii = 0; ii < 8; ++ii)
      Xt[swz128(col + ii, r)] = f2bf(xs[ii]);
  }
  if (tid < T) {
    float cls = clsp[(size_t)bid * T + tid];
    cl2_s[tid]  = cls * 1.44269504088896f;
    ecls_s[tid] = expf(cls);
    onem_s[tid] = onemp[(size_t)bid * T + tid];
  }
  __syncthreads();

  const int tr = w * 16, lr = l & 15, kg = l >> 4;

  short8 aC0 = *(const short8*)&Cl[swz64(tr + lr,      kg * 8)];
  short8 aC1 = *(const short8*)&Cl[swz64(tr + lr, 32 + kg * 8)];

  // matmul1: Z = C @ h0  (acc over d-tiles)
  f32x4 acc[4];
  #pragma unroll
  for (int nt = 0; nt < 4; ++nt) { acc[nt][0]=0.f; acc[nt][1]=0.f; acc[nt][2]=0.f; acc[nt][3]=0.f; }
  #pragma unroll
  for (int nt = 0; nt < 4; ++nt) {
    short8 f0 = *(const short8*)&Hl[swz64(nt * 16 + lr,      kg * 8)];
    short8 f1 = *(const short8*)&Hl[swz64(nt * 16 + lr, 32 + kg * 8)];
    acc[nt] = __builtin_amdgcn_mfma_f32_16x16x32_bf16(aC0, f0, acc[nt], 0, 0, 0);
    acc[nt] = __builtin_amdgcn_mfma_f32_16x16x32_bf16(aC1, f1, acc[nt], 0, 0, 0);
  }
  float e0 = ecls_s[tr + kg * 4 + 0], e1 = ecls_s[tr + kg * 4 + 1];
  float e2 = ecls_s[tr + kg * 4 + 2], e3 = ecls_s[tr + kg * 4 + 3];
  #pragma unroll
  for (int nt = 0; nt < 4; ++nt) {
    acc[nt][0] *= e0; acc[nt][1] *= e1; acc[nt][2] *= e2; acc[nt][3] *= e3;
  }

  // matmul2: G = C @ B^T  (8 j-tiles)
  f32x4 g[8];
  #pragma unroll
  for (int nt = 0; nt < 8; ++nt) { g[nt][0]=0.f; g[nt][1]=0.f; g[nt][2]=0.f; g[nt][3]=0.f; }
  #pragma unroll
  for (int nt = 0; nt < 8; ++nt) {
    short8 f0 = *(const short8*)&Bl[swz64(nt * 16 + lr,      kg * 8)];
    short8 f1 = *(const short8*)&Bl[swz64(nt * 16 + lr, 32 + kg * 8)];
    g[nt] = __builtin_amdgcn_mfma_f32_16x16x32_bf16(aC0, f0, g[nt], 0, 0, 0);
    g[nt] = __builtin_amdgcn_mfma_f32_16x16x32_bf16(aC1, f1, g[nt], 0, 0, 0);
  }
  float c2r[4] = {cl2_s[tr + kg * 4 + 0], cl2_s[tr + kg * 4 + 1],
                  cl2_s[tr + kg * 4 + 2], cl2_s[tr + kg * 4 + 3]};
  #pragma unroll
  for (int nt = 0; nt < 8; ++nt) {
    int j = nt * 16 + lr;
    float c2j = cl2_s[j], om = onem_s[j];
    #pragma unroll
    for (int reg = 0; reg < 4; ++reg) {
      int t = tr + kg * 4 + reg;
      float wgt = (t >= j) ? exp2f(c2r[reg] - c2j) * om : 0.f;
      g[nt][reg] *= wgt;
    }
  }
  __syncthreads();   // all Cl/Bl/Hl fragment reads done; CB reusable as WG

  #pragma unroll
  for (int nt = 0; nt < 8; ++nt)
    #pragma unroll
    for (int reg = 0; reg < 4; ++reg)
      WG[swz128(tr + kg * 4 + reg, nt * 16 + lr)] = f2bf(g[nt][reg]);
  __syncthreads();

  // matmul3: Y += WG @ X   (K = 128)
  short8 aW[4];
  #pragma unroll
  for (int kk = 0; kk < 4; ++kk)
    aW[kk] = *(const short8*)&WG[swz128(tr + lr, kk * 32 + kg * 8)];
  #pragma unroll
  for (int nt = 0; nt < 4; ++nt)
    #pragma unroll
    for (int kk = 0; kk < 4; ++kk) {
      short8 f = *(const short8*)&Xt[swz128(nt * 16 + lr, kk * 32 + kg * 8)];
      acc[nt] = __builtin_amdgcn_mfma_f32_16x16x32_bf16(aW[kk], f, acc[nt], 0, 0, 0);
    }

  #pragma unroll
  for (int reg = 0; reg < 4; ++reg) {
    int t = tr + kg * 4 + reg;
    #pragma unroll
    for (int nt = 0; nt < 4; ++nt)
      Y[g0 + (size_t)t * (NH * 64) + nt * 16 + lr] = acc[nt][reg];
  }
}

// ---------------------------------------------------------------------------
// Fallback (round-1) path if ws is too small
// ---------------------------------------------------------------------------
__global__ __launch_bounds__(256) void alpha_kernel(
    const float* __restrict__ X, const float* __restrict__ A,
    const float* __restrict__ Bm,
    const float* __restrict__ l2ab, const float* __restrict__ l2b,
    const float* __restrict__ sema,
    float* __restrict__ alpha_out, int total, int H) {
  int tid = blockIdx.x * 256 + threadIdx.x;
  int item = tid >> 4, sub = tid & 15;
  if (item >= total) return;
  const float4 xv = *(const float4*)(X + (size_t)item * 64 + sub * 4);
  const float4 bv = *(const float4*)(Bm + (size_t)item * 64 + sub * 4);
  float sx = xv.x + xv.y + xv.z + xv.w;
  float sb = bv.x * bv.x + bv.y * bv.y + bv.z * bv.z + bv.w * bv.w;
  #pragma unroll
  for (int m = 1; m < 16; m <<= 1) {
    sx += __shfl_xor(sx, m, 64);
    sb += __shfl_xor(sb, m, 64);
  }
  if (sub == 0) {
    int h = item % H;
    float lab_c = fminf(fmaxf(l2ab[h], -3.32f), -0.015f);
    float beta  = exp2f(fminf(fmaxf(l2b[h], -2.f), 2.f));
    float ema   = sema[h] + 1e-6f;
    alpha_out[item] = alpha_formula(A[item], sx * (1.f/64.f), sb * (1.f/64.f),
                                    lab_c, beta, ema);
  }
}

__global__ __launch_bounds__(256) void scan_kernel(
    const float* __restrict__ X, const float* __restrict__ Bm,
    const float* __restrict__ Cm, const float* __restrict__ alpha_in,
    float* __restrict__ Y, int Ln, int H) {
  int bh = blockIdx.x;
  int b = bh / H, h = bh % H;
  int tid = threadIdx.x;
  int d = tid & 63, w = tid >> 6;
  const size_t rowstride = (size_t)H * 64;
  const size_t base = ((size_t)b * Ln * H + h) * 64;
  const size_t abase = (size_t)b * Ln * H + h;
  __shared__ float xb[2][64], bb2[2][64], cb[2][64], ab_s[2];
  __shared__ float red[2][4][64];
  float hreg[16];
  #pragma unroll
  for (int k = 0; k < 16; ++k) hreg[k] = 0.0f;
  if (w == 0)      xb[0][d]  = X[base + d];
  else if (w == 1) bb2[0][d] = Bm[base + d];
  else if (w == 2) cb[0][d]  = Cm[base + d];
  else if (d == 0) ab_s[0]   = alpha_in[abase];
  __syncthreads();
  for (int t = 0; t < Ln; ++t) {
    const int cur = t & 1, nxt = cur ^ 1;
    float regn = 0.0f;
    if (t + 1 < Ln) {
      size_t off = base + (size_t)(t + 1) * rowstride + d;
      if (w == 0)      regn = X[off];
      else if (w == 1) regn = Bm[off];
      else if (w == 2) regn = Cm[off];
      else if (d == 0) regn = alpha_in[abase + (size_t)(t + 1) * H];
    }
    float al = ab_s[cur];
    float xv = xb[cur][d];
    float t1 = (1.0f - al) * xv;
    float p = 0.0f;
    const float4* bp = (const float4*)&bb2[cur][w * 16];
    const float4* cp = (const float4*)&cb[cur][w * 16];
    #pragma unroll
    for (int k4 = 0; k4 < 4; ++k4) {
      float4 b4 = bp[k4]; float4 c4 = cp[k4];
      hreg[k4*4+0] = al * hreg[k4*4+0] + b4.x * t1;  p += c4.x * hreg[k4*4+0];
      hreg[k4*4+1] = al * hreg[k4*4+1] + b4.y * t1;  p += c4.y * hreg[k4*4+1];
      hreg[k4*4+2] = al * hreg[k4*4+2] + b4.z * t1;  p += c4.z * hreg[k4*4+2];
      hreg[k4*4+3] = al * hreg[k4*4+3] + b4.w * t1;  p += c4.w * hreg[k4*4+3];
    }
    red[cur][w][d] = p;
    if (t + 1 < Ln) {
      if (w == 0)      xb[nxt][d]  = regn;
      else if (w == 1) bb2[nxt][d] = regn;
      else if (w == 2) cb[nxt][d]  = regn;
      else if (d == 0) ab_s[nxt]   = regn;
    }
    __syncthreads();
    if (w == 0) {
      float y = red[cur][0][d] + red[cur][1][d] + red[cur][2][d] + red[cur][3][d];
      Y[base + (size_t)t * rowstride + d] = y;
    }
  }
}

extern "C" void kernel_launch(void* const* d_in, const int* in_sizes, int n_in,
                              void* d_out, int out_size, void* d_ws, size_t ws_size,
                              hipStream_t stream) {
  const float* X    = (const float*)d_in[0];
  const float* A    = (const float*)d_in[1];
  const float* Bm   = (const float*)d_in[2];
  const float* Cm   = (const float*)d_in[3];
  const float* l2ab = (const float*)d_in[4];
  const float* l2b  = (const float*)d_in[5];
  const float* sema = (const float*)d_in[6];
  float* Y = (float*)d_out;
  char* wsb = (char*)d_ws;

  if (ws_size >= WS_BYTES) {
    unsigned short* Sp   = (unsigned short*)(wsb + S_OFF);
    unsigned short* H0   = (unsigned short*)(wsb + H0_OFF);
    float* lamp          = (float*)(wsb + LAM_OFF);
    float* clsp          = (float*)(wsb + CLS_OFF);
    float* onemp         = (float*)(wsb + ONEM_OFF);
    phase1<<<BH * NC, 256, 0, stream>>>(X, A, Bm, l2ab, l2b, sema,
                                        Sp, lamp, clsp, onemp);
    phase2<<<(BH * 2048) / 256, 256, 0, stream>>>((const unsigned int*)Sp, lamp,
                                                  (unsigned int*)H0);
    phase3<<<BH * NC, 512, 0, stream>>>(X, Bm, Cm, H0, clsp, onemp, Y);
  } else {
    const int total = BATCH * L * NH;
    alpha_kernel<<<(total * 16) / 256, 256, 0, stream>>>(X, A, Bm, l2ab, l2b,
                                                         sema, (float*)wsb, total, NH);
    scan_kernel<<<BH, 256, 0, stream>>>(X, Bm, Cm, (float*)wsb, Y, L, NH);
  }
}

// Round 8
// 55.833 us; speedup vs baseline: 1.2128x; 1.2128x over previous
//
#include <hip/hip_runtime.h>
#include <hip/hip_bf16.h>
#include <math.h>

constexpr int BATCH = 2, L = 4096, NH = 16;
constexpr int T = 64;              // chunk length
constexpr int NC = L / T;          // 64 chunks
constexpr int BH = BATCH * NH;     // 32 chains

// ws layout (bytes)
constexpr size_t S_OFF    = 0;                                   // bf16 [BH][NC][64*64] (S^T: [d][s])
constexpr size_t S_BYTES  = (size_t)BH * NC * 4096 * 2;
constexpr size_t H0_OFF   = S_OFF + S_BYTES;                     // bf16 [BH][NC][64*64] ([d][s])
constexpr size_t H0_BYTES = (size_t)BH * NC * 4096 * 2;
constexpr size_t LAM_OFF  = H0_OFF + H0_BYTES;                   // f32 [BH][NC]
constexpr size_t LAM_BYTES = (size_t)BH * NC * 4;
constexpr size_t CLS_OFF  = LAM_OFF + LAM_BYTES;                 // f32 [BH][NC][T]
constexpr size_t CLS_BYTES = (size_t)BH * NC * T * 4;
constexpr size_t ONEM_OFF = CLS_OFF + CLS_BYTES;                 // f32 [BH][NC][T]
constexpr size_t WS_BYTES = ONEM_OFF + CLS_BYTES;

typedef __attribute__((ext_vector_type(8))) short short8;
typedef __attribute__((ext_vector_type(4))) float f32x4;
typedef __attribute__((ext_vector_type(4))) unsigned int uint4v;

// f32 -> bf16 via compiler cvt path (v_cvt_pk_bf16_f32 on gfx950), RTNE
__device__ __forceinline__ unsigned short f2bf(float f) {
  union { __hip_bfloat16 h; unsigned short u; } v;
  v.h = __float2bfloat16(f);
  return v.u;
}
__device__ __forceinline__ unsigned int pk2(float a, float b) {
  union { __hip_bfloat162 h; unsigned int u; } v;
  v.h = __float22bfloat162_rn(make_float2(a, b));
  return v.u;
}
__device__ __forceinline__ float bf2f(unsigned short u) {
  union { unsigned u; float f; } v; v.u = (unsigned)u << 16;
  return v.f;
}

// swizzled u16 index into a [64][64] bf16 LDS tile (16B-granular XOR swizzle)
__device__ __forceinline__ int swz(int row, int col) {
  return row * 64 + (col ^ ((row & 7) << 3));
}

__device__ __forceinline__ float alpha_formula(float Aval, float xbar, float bsq,
                                               float lab_c, float beta, float ema) {
  float ad = expf(Aval);
  float ab = 1.f - exp2f(lab_c);
  float om = 1.f - ad;
  float ns = om * om * xbar * xbar * bsq / ema;
  float boost = fmaxf(tanhf(beta * ns), 0.f);
  return fminf(fmaxf(ab + (1.f - ab) * boost, 0.01f), 0.999f);
}

// ---------------------------------------------------------------------------
// Phase 1 (MFMA): per (bh, chunk): alpha/cls/coeff;
//   S^T[d][s] = sum_j X[j][d] coeff[j] B[j][s]   (stored bf16, LDS-repacked)
// ---------------------------------------------------------------------------
__global__ __launch_bounds__(256) void phase1(
    const float* __restrict__ X, const float* __restrict__ A,
    const float* __restrict__ Bm,
    const float* __restrict__ l2ab, const float* __restrict__ l2b,
    const float* __restrict__ sema,
    unsigned short* __restrict__ Sp, float* __restrict__ lamp,
    float* __restrict__ clsp, float* __restrict__ onemp) {
  const int bid = blockIdx.x;                 // bh*NC + c
  const int bh = bid >> 6, c = bid & 63;
  const int b = bh >> 4, h = bh & 15;
  const int tid = threadIdx.x;
  const int r = tid >> 2, q = tid & 3;        // row j=r, col-quarter q

  __shared__ unsigned short Xt[64 * 64];      // X^T [d][j]  bf16 swizzled; later S repack
  __shared__ unsigned short Bt[64 * 64];      // (coeff B)^T [s][j] bf16 swizzled
  __shared__ float xb_s[T], bq_s[T], coeff_s[T];

  const size_t g0 = ((size_t)(b * L + c * T) * NH + h) * 64;
  const size_t grow = g0 + (size_t)r * (NH * 64);

  float xr[16], br[16];
  #pragma unroll
  for (int i = 0; i < 4; ++i) {
    *(float4*)&xr[i * 4] = *(const float4*)(X + grow + q * 16 + i * 4);
    *(float4*)&br[i * 4] = *(const float4*)(Bm + grow + q * 16 + i * 4);
  }
  float sx = 0.f, sb = 0.f;
  #pragma unroll
  for (int i = 0; i < 16; ++i) { sx += xr[i]; sb += br[i] * br[i]; }
  sx += __shfl_xor(sx, 1, 64); sx += __shfl_xor(sx, 2, 64);
  sb += __shfl_xor(sb, 1, 64); sb += __shfl_xor(sb, 2, 64);
  if (q == 0) { xb_s[r] = sx * (1.f / 64.f); bq_s[r] = sb * (1.f / 64.f); }

  // stage X^T (scatter transpose)
  #pragma unroll
  for (int i = 0; i < 16; ++i)
    Xt[swz(q * 16 + i, r)] = f2bf(xr[i]);
  __syncthreads();

  if (tid < 64) {
    float lab_c = fminf(fmaxf(l2ab[h], -3.32f), -0.015f);
    float beta  = exp2f(fminf(fmaxf(l2b[h], -2.f), 2.f));
    float ema   = sema[h] + 1e-6f;
    float Aval  = A[(size_t)(b * L + c * T + tid) * NH + h];
    float al = alpha_formula(Aval, xb_s[tid], bq_s[tid], lab_c, beta, ema);
    float onem = 1.f - al;
    float cls = logf(al);
    #pragma unroll
    for (int off = 1; off < 64; off <<= 1) {
      float o = __shfl_up(cls, off, 64);
      if (tid >= off) cls += o;
    }
    float cls63 = __shfl(cls, 63, 64);
    coeff_s[tid] = expf(cls63 - cls) * onem;
    size_t cb = (size_t)bid * T;
    clsp[cb + tid]  = cls;
    onemp[cb + tid] = onem;
    if (tid == 63) lamp[bid] = expf(cls63);
  }
  __syncthreads();

  // stage (coeff * B)^T (scatter transpose)
  {
    float cf = coeff_s[r];
    #pragma unroll
    for (int i = 0; i < 16; ++i)
      Bt[swz(q * 16 + i, r)] = f2bf(cf * br[i]);
  }
  __syncthreads();

  // MFMA: S^T[d][s]; wave w owns d-rows [16w, 16w+16)
  const int l = tid & 63, w = tid >> 6;
  const int tr = w * 16, lr = l & 15, kg = l >> 4;
  short8 aX0 = *(const short8*)&Xt[swz(tr + lr,      kg * 8)];
  short8 aX1 = *(const short8*)&Xt[swz(tr + lr, 32 + kg * 8)];
  f32x4 acc[4];
  #pragma unroll
  for (int nt = 0; nt < 4; ++nt) { acc[nt][0]=0.f; acc[nt][1]=0.f; acc[nt][2]=0.f; acc[nt][3]=0.f; }
  #pragma unroll
  for (int nt = 0; nt < 4; ++nt) {
    short8 f0 = *(const short8*)&Bt[swz(nt * 16 + lr,      kg * 8)];
    short8 f1 = *(const short8*)&Bt[swz(nt * 16 + lr, 32 + kg * 8)];
    acc[nt] = __builtin_amdgcn_mfma_f32_16x16x32_bf16(aX0, f0, acc[nt], 0, 0, 0);
    acc[nt] = __builtin_amdgcn_mfma_f32_16x16x32_bf16(aX1, f1, acc[nt], 0, 0, 0);
  }

  __syncthreads();   // all Xt/Bt fragment reads complete; Xt reusable
  // repack S (bf16) into LDS, swizzled; rows d, cols s
  #pragma unroll
  for (int nt = 0; nt < 4; ++nt)
    #pragma unroll
    for (int reg = 0; reg < 4; ++reg)
      Xt[swz(tr + kg * 4 + reg, nt * 16 + lr)] = f2bf(acc[nt][reg]);
  __syncthreads();

  // coalesced copy-out: 512 short8 groups; thread handles groups tid and 256+tid
  unsigned short* Sb = Sp + (size_t)bid * 4096;
  #pragma unroll
  for (int g2 = 0; g2 < 2; ++g2) {
    int g = g2 * 256 + tid;        // 0..511
    int row = g >> 3, c8 = (g & 7) * 8;
    short8 v = *(const short8*)&Xt[swz(row, c8)];
    *(short8*)(Sb + row * 64 + c8) = v;
  }
}

// ---------------------------------------------------------------------------
// Phase 2: exclusive chunk-scan; reads S (bf16), writes h0 (bf16).
// Recurrence stays in f32 registers; rounding is I/O-only. Deep unroll keeps
// ~16 loads in flight per thread (only 2 waves/SIMD available here).
// ---------------------------------------------------------------------------
__global__ __launch_bounds__(256) void phase2(
    const unsigned int* __restrict__ Sp, const float* __restrict__ lamp,
    unsigned int* __restrict__ H0) {
  const int gtid = blockIdx.x * 256 + threadIdx.x;   // BH*2048 threads
  const int bh = gtid >> 11;
  const int e2 = gtid & 2047;                        // u32 (pair) index in chunk
  const float* lam = lamp + (size_t)bh * NC;
  const size_t base = (size_t)bh * NC * 2048 + e2;   // u32 units
  float h0v = 0.f, h1v = 0.f;
  #pragma unroll 16
  for (int c = 0; c < NC; ++c) {
    size_t off = base + (size_t)c * 2048;
    unsigned v = Sp[off];
    H0[off] = pk2(h0v, h1v);
    float la = lam[c];
    h0v = la * h0v + bf2f((unsigned short)(v & 0xFFFFu));
    h1v = la * h1v + bf2f((unsigned short)(v >> 16));
  }
}

// ---------------------------------------------------------------------------
// Phase 3 (MFMA): Y = diag(e^cls) (C @ h0) + (W ⊙ (C @ B^T)) @ X
// ---------------------------------------------------------------------------
__global__ __launch_bounds__(256) void phase3(
    const float* __restrict__ X, const float* __restrict__ Bm,
    const float* __restrict__ Cm, const unsigned short* __restrict__ H0,
    const float* __restrict__ clsp, const float* __restrict__ onemp,
    float* __restrict__ Y) {
  const int bid = blockIdx.x;
  const int bh = bid >> 6, c = bid & 63;
  const int b = bh >> 4, h = bh & 15;
  const int tid = threadIdx.x;
  const int l = tid & 63, w = tid >> 6;

  __shared__ unsigned short Cl[64 * 64];  // C  [t][s]  (A-op)
  __shared__ unsigned short Bl[64 * 64];  // B  [j][s]  (B-op of C B^T)
  __shared__ unsigned short Hl[64 * 64];  // h0^T [d][s]; later WG [t][j]
  __shared__ unsigned short Xt[64 * 64];  // X^T [d][j]
  __shared__ float cl2_s[64], onem_s[64], ecls_s[64];

  const size_t g0 = ((size_t)(b * L + c * T) * NH + h) * 64;
  const int r = tid >> 2, q = tid & 3;
  const size_t grow = g0 + (size_t)r * (NH * 64);
  const unsigned short* h0p = H0 + (size_t)bid * 4096;

  #pragma unroll
  for (int i = 0; i < 2; ++i) {
    int col = q * 16 + i * 8;
    float4 c0 = *(const float4*)(Cm + grow + col);
    float4 c1 = *(const float4*)(Cm + grow + col + 4);
    float4 b0 = *(const float4*)(Bm + grow + col);
    float4 b1 = *(const float4*)(Bm + grow + col + 4);
    float4 x0 = *(const float4*)(X + grow + col);
    float4 x1 = *(const float4*)(X + grow + col + 4);
    short8 hv = *(const short8*)(h0p + (size_t)r * 64 + col);   // bf16 direct
    int o = swz(r, col);
    uint4v cv = { pk2(c0.x, c0.y), pk2(c0.z, c0.w), pk2(c1.x, c1.y), pk2(c1.z, c1.w) };
    uint4v bv = { pk2(b0.x, b0.y), pk2(b0.z, b0.w), pk2(b1.x, b1.y), pk2(b1.z, b1.w) };
    *(uint4v*)&Cl[o] = cv;
    *(uint4v*)&Bl[o] = bv;
    *(short8*)&Hl[o] = hv;
    float xs[8] = {x0.x, x0.y, x0.z, x0.w, x1.x, x1.y, x1.z, x1.w};
    #pragma unroll
    for (int ii = 0; ii < 8; ++ii)
      Xt[swz(col + ii, r)] = f2bf(xs[ii]);
  }
  if (tid < 64) {
    float cls = clsp[(size_t)bid * T + tid];
    cl2_s[tid]  = cls * 1.44269504088896f;
    ecls_s[tid] = expf(cls);
    onem_s[tid] = onemp[(size_t)bid * T + tid];
  }
  __syncthreads();

  const int tr = w * 16, lr = l & 15, kg = l >> 4;

  short8 aC0 = *(const short8*)&Cl[swz(tr + lr,      kg * 8)];
  short8 aC1 = *(const short8*)&Cl[swz(tr + lr, 32 + kg * 8)];

  // matmul1: Z = C @ h0
  f32x4 acc[4];
  #pragma unroll
  for (int nt = 0; nt < 4; ++nt) { acc[nt][0]=0.f; acc[nt][1]=0.f; acc[nt][2]=0.f; acc[nt][3]=0.f; }
  #pragma unroll
  for (int nt = 0; nt < 4; ++nt) {
    short8 f0 = *(const short8*)&Hl[swz(nt * 16 + lr,      kg * 8)];
    short8 f1 = *(const short8*)&Hl[swz(nt * 16 + lr, 32 + kg * 8)];
    acc[nt] = __builtin_amdgcn_mfma_f32_16x16x32_bf16(aC0, f0, acc[nt], 0, 0, 0);
    acc[nt] = __builtin_amdgcn_mfma_f32_16x16x32_bf16(aC1, f1, acc[nt], 0, 0, 0);
  }
  float e0 = ecls_s[tr + kg * 4 + 0], e1 = ecls_s[tr + kg * 4 + 1];
  float e2 = ecls_s[tr + kg * 4 + 2], e3 = ecls_s[tr + kg * 4 + 3];
  #pragma unroll
  for (int nt = 0; nt < 4; ++nt) {
    acc[nt][0] *= e0; acc[nt][1] *= e1; acc[nt][2] *= e2; acc[nt][3] *= e3;
  }

  // matmul2: G = C @ B^T
  f32x4 g[4];
  #pragma unroll
  for (int nt = 0; nt < 4; ++nt) { g[nt][0]=0.f; g[nt][1]=0.f; g[nt][2]=0.f; g[nt][3]=0.f; }
  #pragma unroll
  for (int nt = 0; nt < 4; ++nt) {
    short8 f0 = *(const short8*)&Bl[swz(nt * 16 + lr,      kg * 8)];
    short8 f1 = *(const short8*)&Bl[swz(nt * 16 + lr, 32 + kg * 8)];
    g[nt] = __builtin_amdgcn_mfma_f32_16x16x32_bf16(aC0, f0, g[nt], 0, 0, 0);
    g[nt] = __builtin_amdgcn_mfma_f32_16x16x32_bf16(aC1, f1, g[nt], 0, 0, 0);
  }
  float c2r[4] = {cl2_s[tr + kg * 4 + 0], cl2_s[tr + kg * 4 + 1],
                  cl2_s[tr + kg * 4 + 2], cl2_s[tr + kg * 4 + 3]};
  #pragma unroll
  for (int nt = 0; nt < 4; ++nt) {
    int j = nt * 16 + lr;
    float c2j = cl2_s[j], om = onem_s[j];
    #pragma unroll
    for (int reg = 0; reg < 4; ++reg) {
      int t = tr + kg * 4 + reg;
      float wgt = (t >= j) ? exp2f(c2r[reg] - c2j) * om : 0.f;
      g[nt][reg] *= wgt;
    }
  }
  __syncthreads();

  #pragma unroll
  for (int nt = 0; nt < 4; ++nt)
    #pragma unroll
    for (int reg = 0; reg < 4; ++reg)
      Hl[swz(tr + kg * 4 + reg, nt * 16 + lr)] = f2bf(g[nt][reg]);
  __syncthreads();

  // matmul3: Y += WG @ X
  short8 aW0 = *(const short8*)&Hl[swz(tr + lr,      kg * 8)];
  short8 aW1 = *(const short8*)&Hl[swz(tr + lr, 32 + kg * 8)];
  #pragma unroll
  for (int nt = 0; nt < 4; ++nt) {
    short8 f0 = *(const short8*)&Xt[swz(nt * 16 + lr,      kg * 8)];
    short8 f1 = *(const short8*)&Xt[swz(nt * 16 + lr, 32 + kg * 8)];
    acc[nt] = __builtin_amdgcn_mfma_f32_16x16x32_bf16(aW0, f0, acc[nt], 0, 0, 0);
    acc[nt] = __builtin_amdgcn_mfma_f32_16x16x32_bf16(aW1, f1, acc[nt], 0, 0, 0);
  }

  #pragma unroll
  for (int reg = 0; reg < 4; ++reg) {
    int t = tr + kg * 4 + reg;
    #pragma unroll
    for (int nt = 0; nt < 4; ++nt)
      Y[g0 + (size_t)t * (NH * 64) + nt * 16 + lr] = acc[nt][reg];
  }
}

// ---------------------------------------------------------------------------
// Fallback (round-1) path if ws is too small
// ---------------------------------------------------------------------------
__global__ __launch_bounds__(256) void alpha_kernel(
    const float* __restrict__ X, const float* __restrict__ A,
    const float* __restrict__ Bm,
    const float* __restrict__ l2ab, const float* __restrict__ l2b,
    const float* __restrict__ sema,
    float* __restrict__ alpha_out, int total, int H) {
  int tid = blockIdx.x * 256 + threadIdx.x;
  int item = tid >> 4, sub = tid & 15;
  if (item >= total) return;
  const float4 xv = *(const float4*)(X + (size_t)item * 64 + sub * 4);
  const float4 bv = *(const float4*)(Bm + (size_t)item * 64 + sub * 4);
  float sx = xv.x + xv.y + xv.z + xv.w;
  float sb = bv.x * bv.x + bv.y * bv.y + bv.z * bv.z + bv.w * bv.w;
  #pragma unroll
  for (int m = 1; m < 16; m <<= 1) {
    sx += __shfl_xor(sx, m, 64);
    sb += __shfl_xor(sb, m, 64);
  }
  if (sub == 0) {
    int h = item % H;
    float lab_c = fminf(fmaxf(l2ab[h], -3.32f), -0.015f);
    float beta  = exp2f(fminf(fmaxf(l2b[h], -2.f), 2.f));
    float ema   = sema[h] + 1e-6f;
    alpha_out[item] = alpha_formula(A[item], sx * (1.f/64.f), sb * (1.f/64.f),
                                    lab_c, beta, ema);
  }
}

__global__ __launch_bounds__(256) void scan_kernel(
    const float* __restrict__ X, const float* __restrict__ Bm,
    const float* __restrict__ Cm, const float* __restrict__ alpha_in,
    float* __restrict__ Y, int Ln, int H) {
  int bh = blockIdx.x;
  int b = bh / H, h = bh % H;
  int tid = threadIdx.x;
  int d = tid & 63, w = tid >> 6;
  const size_t rowstride = (size_t)H * 64;
  const size_t base = ((size_t)b * Ln * H + h) * 64;
  const size_t abase = (size_t)b * Ln * H + h;
  __shared__ float xb[2][64], bb2[2][64], cb[2][64], ab_s[2];
  __shared__ float red[2][4][64];
  float hreg[16];
  #pragma unroll
  for (int k = 0; k < 16; ++k) hreg[k] = 0.0f;
  if (w == 0)      xb[0][d]  = X[base + d];
  else if (w == 1) bb2[0][d] = Bm[base + d];
  else if (w == 2) cb[0][d]  = Cm[base + d];
  else if (d == 0) ab_s[0]   = alpha_in[abase];
  __syncthreads();
  for (int t = 0; t < Ln; ++t) {
    const int cur = t & 1, nxt = cur ^ 1;
    float regn = 0.0f;
    if (t + 1 < Ln) {
      size_t off = base + (size_t)(t + 1) * rowstride + d;
      if (w == 0)      regn = X[off];
      else if (w == 1) regn = Bm[off];
      else if (w == 2) regn = Cm[off];
      else if (d == 0) regn = alpha_in[abase + (size_t)(t + 1) * H];
    }
    float al = ab_s[cur];
    float xv = xb[cur][d];
    float t1 = (1.0f - al) * xv;
    float p = 0.0f;
    const float4* bp = (const float4*)&bb2[cur][w * 16];
    const float4* cp = (const float4*)&cb[cur][w * 16];
    #pragma unroll
    for (int k4 = 0; k4 < 4; ++k4) {
      float4 b4 = bp[k4]; float4 c4 = cp[k4];
      hreg[k4*4+0] = al * hreg[k4*4+0] + b4.x * t1;  p += c4.x * hreg[k4*4+0];
      hreg[k4*4+1] = al * hreg[k4*4+1] + b4.y * t1;  p += c4.y * hreg[k4*4+1];
      hreg[k4*4+2] = al * hreg[k4*4+2] + b4.z * t1;  p += c4.z * hreg[k4*4+2];
      hreg[k4*4+3] = al * hreg[k4*4+3] + b4.w * t1;  p += c4.w * hreg[k4*4+3];
    }
    red[cur][w][d] = p;
    if (t + 1 < Ln) {
      if (w == 0)      xb[nxt][d]  = regn;
      else if (w == 1) bb2[nxt][d] = regn;
      else if (w == 2) cb[nxt][d]  = regn;
      else if (d == 0) ab_s[nxt]   = regn;
    }
    __syncthreads();
    if (w == 0) {
      float y = red[cur][0][d] + red[cur][1][d] + red[cur][2][d] + red[cur][3][d];
      Y[base + (size_t)t * rowstride + d] = y;
    }
  }
}

extern "C" void kernel_launch(void* const* d_in, const int* in_sizes, int n_in,
                              void* d_out, int out_size, void* d_ws, size_t ws_size,
                              hipStream_t stream) {
  const float* X    = (const float*)d_in[0];
  const float* A    = (const float*)d_in[1];
  const float* Bm   = (const float*)d_in[2];
  const float* Cm   = (const float*)d_in[3];
  const float* l2ab = (const float*)d_in[4];
  const float* l2b  = (const float*)d_in[5];
  const float* sema = (const float*)d_in[6];
  float* Y = (float*)d_out;
  char* wsb = (char*)d_ws;

  if (ws_size >= WS_BYTES) {
    unsigned short* Sp   = (unsigned short*)(wsb + S_OFF);
    unsigned short* H0   = (unsigned short*)(wsb + H0_OFF);
    float* lamp          = (float*)(wsb + LAM_OFF);
    float* clsp          = (float*)(wsb + CLS_OFF);
    float* onemp         = (float*)(wsb + ONEM_OFF);
    phase1<<<BH * NC, 256, 0, stream>>>(X, A, Bm, l2ab, l2b, sema,
                                        Sp, lamp, clsp, onemp);
    phase2<<<(BH * 2048) / 256, 256, 0, stream>>>((const unsigned int*)Sp, lamp,
                                                  (unsigned int*)H0);
    phase3<<<BH * NC, 256, 0, stream>>>(X, Bm, Cm, H0, clsp, onemp, Y);
  } else {
    const int total = BATCH * L * NH;
    alpha_kernel<<<(total * 16) / 256, 256, 0, stream>>>(X, A, Bm, l2ab, l2b,
                                                         sema, (float*)wsb, total, NH);
    scan_kernel<<<BH, 256, 0, stream>>>(X, Bm, Cm, (float*)wsb, Y, L, NH);
  }
}